// Round 7
// baseline (60.844 us; speedup 1.0000x reference)
//
#include <hip/hip_runtime.h>
#include <hip/hip_bf16.h>

#define BATCH 8
#define SEQ   8192
#define DIM   512

typedef float f32x4 __attribute__((ext_vector_type(4)));
typedef unsigned short u16x8 __attribute__((ext_vector_type(8)));

#define INV2PI   0.15915494309189535f
#define SQRT_DIM 22.62741699796952f
// -log2(10000)/256  (div[k] = 2^(C2*k) = exp(-2k*ln(10000)/512))
#define C2 (-0.05190512648261504f)

// Workspace: [0,256KB) seg ids (int32), [256KB, +8MB) pe table (bf16)
#define SEG_BYTES ((size_t)BATCH * SEQ * 4)
#define PE_BYTES  ((size_t)SEQ * DIM * 2)

#define TPB_PREP  1024
#define SEG_CHUNK (SEQ / TPB_PREP)          // 8 tokens / thread
#define NWAVE     (TPB_PREP / 64)           // 16
#define PE_ROWS_PER_BLOCK NWAVE             // 16 rows (1 wave = 1 row)
#define PE_BLOCKS (SEQ / PE_ROWS_PER_BLOCK) // 512

// LDS index, +1 int per 8: addr = 9t+j -> 2-way bank alias only (free)
#define TIX(k) ((k) + ((k) >> 3))

// ---------------------------------------------------------------------------
// prep_kernel
//   blocks [0,8)     : segment-id scan, one block (1024 thr) per batch row
//   blocks [8,8+512) : bf16 pe table fill, 16 rows/block, lane-contiguous
//
// seg reference (step i = 1..SEQ-1, carry nc starts 0):
//   c=t[i]; p=t[i-1];
//   if (36<=c<=41) nc=2;
//   is_note = c<12;
//   flag = is_note ? ((p>=12)||(nc>0)) : (p<12);
//   if (is_note) nc-=1;
//   seg = inclusive cumsum of flags (flag for token 0 = 0)
//
// nc chunk transform (reset,val): T(nc)=reset?val:nc+val; applied to nc=0 the
// prefix value is just val. compose(earlier A, later B) =
//   B.reset ? B : {A.reset, A.val+B.val}.
// ---------------------------------------------------------------------------
__global__ __launch_bounds__(TPB_PREP)
void prep_kernel(const int* __restrict__ tok, int* __restrict__ seg,
                 __hip_bfloat16* __restrict__ pe) {
    const int tid  = threadIdx.x;
    const int lane = tid & 63;
    const int wv   = tid >> 6;

    if (blockIdx.x >= BATCH) {
        // ------------------- bf16 pe table fill -------------------------
        const int pos = ((int)blockIdx.x - BATCH) * PE_ROWS_PER_BLOCK + wv;
        const float posf = (float)pos;
        const int d0 = lane << 3;            // elements [d0, d0+8)

        u16x8 v;
        #pragma unroll
        for (int j = 0; j < 4; ++j) {
            const float k = (float)((d0 >> 1) + j);
            const float div = __builtin_amdgcn_exp2f(C2 * k);
            float r = posf * div * INV2PI;  r -= floorf(r);
            const float s = __builtin_amdgcn_sinf(r);
            const float c = __builtin_amdgcn_cosf(r);
            v[2 * j]     = __bfloat16_as_ushort(__float2bfloat16(s));
            v[2 * j + 1] = __bfloat16_as_ushort(__float2bfloat16(c));
        }
        *reinterpret_cast<u16x8*>(pe + (size_t)pos * DIM + d0) = v;
        return;
    }

    // --------------------------- segment scan ----------------------------
    __shared__ int s_tok[SEQ + SEQ / 8];   // 36 KB
    __shared__ int s_seg[SEQ + SEQ / 8];   // 36 KB
    __shared__ int s_pr[NWAVE], s_pv[NWAVE], s_cnt[NWAVE];

    const int b  = blockIdx.x;
    const int* t = tok + (size_t)b * SEQ;
    int*      sg = seg + (size_t)b * SEQ;

    #pragma unroll
    for (int m = 0; m < SEG_CHUNK; ++m) {
        const int k = m * TPB_PREP + tid;
        s_tok[TIX(k)] = t[k];
    }
    __syncthreads();

    const int start = tid * SEG_CHUNK;
    const int end   = start + SEG_CHUNK;
    const int lo    = (start < 1) ? 1 : start;

    // ---- pass 1: per-thread nc transform --------------------------------
    int reset = 0, val = 0;
    #pragma unroll
    for (int i = lo; i < end; ++i) {
        const int c = s_tok[TIX(i)];
        if (c >= 36 && c <= 41) { reset = 1; val = 2; }
        if (c < 12) val -= 1;
    }

    int ir = reset, iv = val;
    #pragma unroll
    for (int off = 1; off < 64; off <<= 1) {
        const int pv = __shfl_up(iv, off);
        const int pr = __shfl_up(ir, off);
        if (lane >= off && !ir) { iv += pv; ir = pr; }
    }
    int er = __shfl_up(ir, 1), ev = __shfl_up(iv, 1);
    if (lane == 0) { er = 0; ev = 0; }
    if (lane == 63) { s_pr[wv] = ir; s_pv[wv] = iv; }
    __syncthreads();
    int bv = 0;
    for (int w = 0; w < wv; ++w) {
        const int r2 = s_pr[w], v2 = s_pv[w];
        if (r2) bv = v2; else bv += v2;
    }
    const int nc_entry = er ? ev : (bv + ev);

    // ---- pass 2: per-thread flag count ----------------------------------
    int nc = nc_entry, total = 0;
    #pragma unroll
    for (int i = lo; i < end; ++i) {
        const int c = s_tok[TIX(i)];
        const int p = s_tok[TIX(i - 1)];
        if (c >= 36 && c <= 41) nc = 2;
        const bool is_note = (c < 12);
        const int f = is_note ? (int)((p >= 12) || (nc > 0)) : (int)(p < 12);
        if (is_note) nc -= 1;
        total += f;
    }

    int it = total;
    #pragma unroll
    for (int off = 1; off < 64; off <<= 1) {
        const int pv = __shfl_up(it, off);
        if (lane >= off) it += pv;
    }
    int et = __shfl_up(it, 1);
    if (lane == 0) et = 0;
    if (lane == 63) s_cnt[wv] = it;
    __syncthreads();
    int boff = 0;
    for (int w = 0; w < wv; ++w) boff += s_cnt[w];
    int run = boff + et;

    // ---- pass 3: recompute flags, cumsum into LDS, flush coalesced ------
    nc = nc_entry;
    if (start == 0) s_seg[TIX(0)] = 0;
    #pragma unroll
    for (int i = lo; i < end; ++i) {
        const int c = s_tok[TIX(i)];
        const int p = s_tok[TIX(i - 1)];
        if (c >= 36 && c <= 41) nc = 2;
        const bool is_note = (c < 12);
        const int f = is_note ? (int)((p >= 12) || (nc > 0)) : (int)(p < 12);
        if (is_note) nc -= 1;
        run += f;
        s_seg[TIX(i)] = run;
    }
    __syncthreads();
    #pragma unroll
    for (int m = 0; m < SEG_CHUNK; ++m) {
        const int k = m * TPB_PREP + tid;
        sg[k] = s_seg[TIX(k)];
    }
}

// ---------------------------------------------------------------------------
// out_kernel: out[row,d] = emb[tok[row],d]*sqrt(512) + pe_bf16[seg[row],d]
//
// XCD slab swizzle (16384 blocks = 8 XCDs x 2048): vb = (bid&7)*2048+bid>>3
// gives each XCD one full batch -> its pe reads stream monotonically through
// its own L2 exactly once (KB-scale active window), no cross-XCD duplication.
//
// 1 wave = 1 row (512 f32). Lane covers 8 contiguous floats:
//   emb: 2x dwordx4 (32B/lane, dense 2KB/wave)
//   pe : 1x dwordx4 of 8 bf16 (16B/lane, dense 1KB/wave)
//   out: 2x NT dwordx4 (write-once, keep L2 for pe)
// row is wave-uniform -> tok/seg via scalar loads. bf16 decode = bits<<16.
// ---------------------------------------------------------------------------
#define OUT_BLOCKS ((BATCH * SEQ) / 4)   // 4 rows / 256-thread block = 16384

__global__ __launch_bounds__(256)
void out_kernel(const int*   __restrict__ tok,
                const int*   __restrict__ seg,
                const float* __restrict__ emb,
                const unsigned short* __restrict__ pe,
                float*       __restrict__ out) {
    // bijective slab swizzle: 16384 = 8 * 2048
    const int bid = (int)blockIdx.x;
    const int vb  = ((bid & 7) << 11) | (bid >> 3);

    const int lane = (int)threadIdx.x & 63;
    const int row  = __builtin_amdgcn_readfirstlane(
                        vb * 4 + ((int)threadIdx.x >> 6));

    const int token = tok[row];   // scalar load (uniform)
    const int sgv   = seg[row];   // scalar load (uniform)

    const int d0 = lane << 3;     // floats [d0, d0+8)

    const float* erow = emb + (size_t)token * DIM + d0;
    const f32x4 e0 = *reinterpret_cast<const f32x4*>(erow);
    const f32x4 e1 = *reinterpret_cast<const f32x4*>(erow + 4);

    const u16x8 pb = *reinterpret_cast<const u16x8*>(pe + (size_t)sgv * DIM + d0);

    float p[8];
    #pragma unroll
    for (int j = 0; j < 8; ++j) {
        const unsigned int bits = ((unsigned int)pb[j]) << 16;
        p[j] = __builtin_bit_cast(float, bits);
    }

    f32x4 o0, o1;
    o0.x = e0.x * SQRT_DIM + p[0];  o0.y = e0.y * SQRT_DIM + p[1];
    o0.z = e0.z * SQRT_DIM + p[2];  o0.w = e0.w * SQRT_DIM + p[3];
    o1.x = e1.x * SQRT_DIM + p[4];  o1.y = e1.y * SQRT_DIM + p[5];
    o1.z = e1.z * SQRT_DIM + p[6];  o1.w = e1.w * SQRT_DIM + p[7];

    float* orow = out + (size_t)row * DIM + d0;
    __builtin_nontemporal_store(o0, reinterpret_cast<f32x4*>(orow));
    __builtin_nontemporal_store(o1, reinterpret_cast<f32x4*>(orow + 4));
}

// ---------------------------------------------------------------------------
// Fallback out (ws too small for pe table): inline trig, same store layout.
// ---------------------------------------------------------------------------
__global__ __launch_bounds__(256)
void out_kernel_trig(const int*   __restrict__ tok,
                     const int*   __restrict__ seg,
                     const float* __restrict__ emb,
                     float*       __restrict__ out) {
    const int bid = (int)blockIdx.x;
    const int vb  = ((bid & 7) << 11) | (bid >> 3);

    const int lane = (int)threadIdx.x & 63;
    const int row  = __builtin_amdgcn_readfirstlane(
                        vb * 4 + ((int)threadIdx.x >> 6));

    const int   token = tok[row];
    const float segf  = (float)seg[row];

    const int d0 = lane << 3;
    const float* erow = emb + (size_t)token * DIM + d0;
    const f32x4 e0 = *reinterpret_cast<const f32x4*>(erow);
    const f32x4 e1 = *reinterpret_cast<const f32x4*>(erow + 4);

    float p[8];
    #pragma unroll
    for (int j = 0; j < 4; ++j) {
        const float k = (float)((d0 >> 1) + j);
        const float div = __builtin_amdgcn_exp2f(C2 * k);
        float r = segf * div * INV2PI;  r -= floorf(r);
        p[2 * j]     = __builtin_amdgcn_sinf(r);
        p[2 * j + 1] = __builtin_amdgcn_cosf(r);
    }

    f32x4 o0, o1;
    o0.x = e0.x * SQRT_DIM + p[0];  o0.y = e0.y * SQRT_DIM + p[1];
    o0.z = e0.z * SQRT_DIM + p[2];  o0.w = e0.w * SQRT_DIM + p[3];
    o1.x = e1.x * SQRT_DIM + p[4];  o1.y = e1.y * SQRT_DIM + p[5];
    o1.z = e1.z * SQRT_DIM + p[6];  o1.w = e1.w * SQRT_DIM + p[7];

    float* orow = out + (size_t)row * DIM + d0;
    __builtin_nontemporal_store(o0, reinterpret_cast<f32x4*>(orow));
    __builtin_nontemporal_store(o1, reinterpret_cast<f32x4*>(orow + 4));
}

extern "C" void kernel_launch(void* const* d_in, const int* in_sizes, int n_in,
                              void* d_out, int out_size, void* d_ws, size_t ws_size,
                              hipStream_t stream) {
    const int*   tok = (const int*)d_in[0];     // (BATCH, SEQ) int32
    const float* emb = (const float*)d_in[1];   // (VOCAB, DIM) f32
    float*       out = (float*)d_out;           // (BATCH, SEQ, DIM) f32
    int*             seg = (int*)d_ws;
    __hip_bfloat16*  pe  = (__hip_bfloat16*)((char*)d_ws + SEG_BYTES);

    const bool have_pe_ws = (ws_size >= SEG_BYTES + PE_BYTES);

    if (have_pe_ws) {
        prep_kernel<<<BATCH + PE_BLOCKS, TPB_PREP, 0, stream>>>(tok, seg, pe);
        out_kernel<<<OUT_BLOCKS, 256, 0, stream>>>(
            tok, seg, emb, (const unsigned short*)pe, out);
    } else {
        prep_kernel<<<BATCH, TPB_PREP, 0, stream>>>(tok, seg, pe);
        out_kernel_trig<<<OUT_BLOCKS, 256, 0, stream>>>(tok, seg, emb, out);
    }
}

// Round 8
// 39.302 us; speedup vs baseline: 1.5481x; 1.5481x over previous
//
#include <hip/hip_runtime.h>
#include <hip/hip_bf16.h>

#define BATCH 8
#define SEQ   8192
#define DIM   512

typedef float f32x4 __attribute__((ext_vector_type(4)));
typedef unsigned short u16x4 __attribute__((ext_vector_type(4)));

#define INV2PI   0.15915494309189535f
#define SQRT_DIM 22.62741699796952f
// -log2(10000)/256  (div[k] = 2^(C2*k) = exp(-2k*ln(10000)/512))
#define C2 (-0.05190512648261504f)

// Workspace: [0,256KB) seg ids (int32), [256KB, +8MB) pe table (bf16)
#define SEG_BYTES ((size_t)BATCH * SEQ * 4)
#define PE_BYTES  ((size_t)SEQ * DIM * 2)

#define TPB_PREP  1024
#define SEG_CHUNK (SEQ / TPB_PREP)          // 8 tokens / thread
#define NWAVE     (TPB_PREP / 64)           // 16
#define PE_ROWS_PER_BLOCK NWAVE             // 16 rows (1 wave = 1 row)
#define PE_BLOCKS (SEQ / PE_ROWS_PER_BLOCK) // 512

// LDS index, +1 int per 8: addr = 9t+j -> 2-way bank alias only (free)
#define TIX(k) ((k) + ((k) >> 3))

// ---------------------------------------------------------------------------
// prep_kernel
//   blocks [0,8)     : segment-id scan, one block (1024 thr) per batch row
//   blocks [8,8+512) : bf16 pe fill, 16 rows/block, dA/dB dense lane layout
//
// seg reference (step i = 1..SEQ-1, carry nc starts 0):
//   c=t[i]; p=t[i-1];
//   if (36<=c<=41) nc=2;
//   is_note = c<12;
//   flag = is_note ? ((p>=12)||(nc>0)) : (p<12);
//   if (is_note) nc-=1;
//   seg = inclusive cumsum of flags (flag for token 0 = 0)
//
// nc chunk transform (reset,val): T(nc)=reset?val:nc+val; applied to nc=0 the
// prefix value is just val. compose(earlier A, later B) =
//   B.reset ? B : {A.reset, A.val+B.val}.
// ---------------------------------------------------------------------------
__global__ __launch_bounds__(TPB_PREP)
void prep_kernel(const int* __restrict__ tok, int* __restrict__ seg,
                 unsigned short* __restrict__ pe) {
    const int tid  = threadIdx.x;
    const int lane = tid & 63;
    const int wv   = tid >> 6;

    if (blockIdx.x >= BATCH) {
        // ------------------- bf16 pe table fill (dA/dB dense) ------------
        const int pos = ((int)blockIdx.x - BATCH) * PE_ROWS_PER_BLOCK + wv;
        const float posf = (float)pos;
        const int dA = lane << 2;        // elements [dA, dA+4)
        const int dB = dA + 256;         // elements [dB, dB+4)

        u16x4 vA, vB;
        #pragma unroll
        for (int j = 0; j < 2; ++j) {
            const float kA = (float)((dA >> 1) + j);
            const float divA = __builtin_amdgcn_exp2f(C2 * kA);
            float rA = posf * divA * INV2PI;  rA -= floorf(rA);
            vA[2 * j]     = __bfloat16_as_ushort(__float2bfloat16(__builtin_amdgcn_sinf(rA)));
            vA[2 * j + 1] = __bfloat16_as_ushort(__float2bfloat16(__builtin_amdgcn_cosf(rA)));

            const float kB = (float)((dB >> 1) + j);
            const float divB = __builtin_amdgcn_exp2f(C2 * kB);
            float rB = posf * divB * INV2PI;  rB -= floorf(rB);
            vB[2 * j]     = __bfloat16_as_ushort(__float2bfloat16(__builtin_amdgcn_sinf(rB)));
            vB[2 * j + 1] = __bfloat16_as_ushort(__float2bfloat16(__builtin_amdgcn_cosf(rB)));
        }
        unsigned short* prow = pe + (size_t)pos * DIM;
        *reinterpret_cast<u16x4*>(prow + dA) = vA;   // 8B/lane, 512B dense/wave
        *reinterpret_cast<u16x4*>(prow + dB) = vB;
        return;
    }

    // --------------------------- segment scan ----------------------------
    __shared__ int s_tok[SEQ + SEQ / 8];   // 36 KB
    __shared__ int s_seg[SEQ + SEQ / 8];   // 36 KB
    __shared__ int s_pr[NWAVE], s_pv[NWAVE], s_cnt[NWAVE];

    const int b  = blockIdx.x;
    const int* t = tok + (size_t)b * SEQ;
    int*      sg = seg + (size_t)b * SEQ;

    #pragma unroll
    for (int m = 0; m < SEG_CHUNK; ++m) {
        const int k = m * TPB_PREP + tid;
        s_tok[TIX(k)] = t[k];
    }
    __syncthreads();

    const int start = tid * SEG_CHUNK;
    const int end   = start + SEG_CHUNK;
    const int lo    = (start < 1) ? 1 : start;

    // ---- pass 1: per-thread nc transform --------------------------------
    int reset = 0, val = 0;
    #pragma unroll
    for (int i = lo; i < end; ++i) {
        const int c = s_tok[TIX(i)];
        if (c >= 36 && c <= 41) { reset = 1; val = 2; }
        if (c < 12) val -= 1;
    }

    int ir = reset, iv = val;
    #pragma unroll
    for (int off = 1; off < 64; off <<= 1) {
        const int pv = __shfl_up(iv, off);
        const int pr = __shfl_up(ir, off);
        if (lane >= off && !ir) { iv += pv; ir = pr; }
    }
    int er = __shfl_up(ir, 1), ev = __shfl_up(iv, 1);
    if (lane == 0) { er = 0; ev = 0; }
    if (lane == 63) { s_pr[wv] = ir; s_pv[wv] = iv; }
    __syncthreads();
    int bv = 0;
    for (int w = 0; w < wv; ++w) {
        const int r2 = s_pr[w], v2 = s_pv[w];
        if (r2) bv = v2; else bv += v2;
    }
    const int nc_entry = er ? ev : (bv + ev);

    // ---- pass 2: per-thread flag count ----------------------------------
    int nc = nc_entry, total = 0;
    #pragma unroll
    for (int i = lo; i < end; ++i) {
        const int c = s_tok[TIX(i)];
        const int p = s_tok[TIX(i - 1)];
        if (c >= 36 && c <= 41) nc = 2;
        const bool is_note = (c < 12);
        const int f = is_note ? (int)((p >= 12) || (nc > 0)) : (int)(p < 12);
        if (is_note) nc -= 1;
        total += f;
    }

    int it = total;
    #pragma unroll
    for (int off = 1; off < 64; off <<= 1) {
        const int pv = __shfl_up(it, off);
        if (lane >= off) it += pv;
    }
    int et = __shfl_up(it, 1);
    if (lane == 0) et = 0;
    if (lane == 63) s_cnt[wv] = it;
    __syncthreads();
    int boff = 0;
    for (int w = 0; w < wv; ++w) boff += s_cnt[w];
    int run = boff + et;

    // ---- pass 3: recompute flags, cumsum into LDS, flush coalesced ------
    nc = nc_entry;
    if (start == 0) s_seg[TIX(0)] = 0;
    #pragma unroll
    for (int i = lo; i < end; ++i) {
        const int c = s_tok[TIX(i)];
        const int p = s_tok[TIX(i - 1)];
        if (c >= 36 && c <= 41) nc = 2;
        const bool is_note = (c < 12);
        const int f = is_note ? (int)((p >= 12) || (nc > 0)) : (int)(p < 12);
        if (is_note) nc -= 1;
        run += f;
        s_seg[TIX(i)] = run;
    }
    __syncthreads();
    #pragma unroll
    for (int m = 0; m < SEG_CHUNK; ++m) {
        const int k = m * TPB_PREP + tid;
        sg[k] = s_seg[TIX(k)];
    }
}

// ---------------------------------------------------------------------------
// out_kernel: out[row,d] = emb[tok[row],d]*sqrt(512) + pe_bf16[seg[row],d]
//
// R5 structure exactly (proven best), single change: pe is bf16.
//  - XCD slab swizzle: vb = (bid&7)*2048 + bid>>3 -> each XCD owns one batch,
//    streams its pe rows monotonically through its own L2 exactly once.
//  - dA/dB dense lane layout: lane covers floats [4L,4L+4) and [256+4L,...).
//    EVERY load/store instruction is a dense wave burst (1KB f32 / 512B bf16)
//    -- required because NT stores bypass L2 and cannot be sector-merged.
//  - row wave-uniform -> tok/seg scalar loads.
//  - NT stores: write-once output, keep L2 for pe.
// ---------------------------------------------------------------------------
#define OUT_BLOCKS ((BATCH * SEQ) / 4)   // 4 rows / 256-thread block = 16384

__global__ __launch_bounds__(256)
void out_kernel(const int*   __restrict__ tok,
                const int*   __restrict__ seg,
                const float* __restrict__ emb,
                const unsigned short* __restrict__ pe,
                float*       __restrict__ out) {
    // bijective slab swizzle: 16384 = 8 * 2048
    const int bid = (int)blockIdx.x;
    const int vb  = ((bid & 7) << 11) | (bid >> 3);

    const int lane = (int)threadIdx.x & 63;
    const int row  = __builtin_amdgcn_readfirstlane(
                        vb * 4 + ((int)threadIdx.x >> 6));

    const int token = tok[row];   // scalar load (uniform)
    const int sgv   = seg[row];   // scalar load (uniform)

    const int dA = lane << 2;
    const int dB = dA + 256;

    const float* erow = emb + (size_t)token * DIM;
    const unsigned short* prow = pe + (size_t)sgv * DIM;

    const f32x4 eA = *reinterpret_cast<const f32x4*>(erow + dA);
    const f32x4 eB = *reinterpret_cast<const f32x4*>(erow + dB);
    const u16x4 bA = *reinterpret_cast<const u16x4*>(prow + dA);
    const u16x4 bB = *reinterpret_cast<const u16x4*>(prow + dB);

    float pA[4], pB[4];
    #pragma unroll
    for (int j = 0; j < 4; ++j) {
        pA[j] = __builtin_bit_cast(float, ((unsigned int)bA[j]) << 16);
        pB[j] = __builtin_bit_cast(float, ((unsigned int)bB[j]) << 16);
    }

    f32x4 oA, oB;
    oA.x = eA.x * SQRT_DIM + pA[0];  oA.y = eA.y * SQRT_DIM + pA[1];
    oA.z = eA.z * SQRT_DIM + pA[2];  oA.w = eA.w * SQRT_DIM + pA[3];
    oB.x = eB.x * SQRT_DIM + pB[0];  oB.y = eB.y * SQRT_DIM + pB[1];
    oB.z = eB.z * SQRT_DIM + pB[2];  oB.w = eB.w * SQRT_DIM + pB[3];

    float* orow = out + (size_t)row * DIM;
    __builtin_nontemporal_store(oA, reinterpret_cast<f32x4*>(orow + dA));
    __builtin_nontemporal_store(oB, reinterpret_cast<f32x4*>(orow + dB));
}

// ---------------------------------------------------------------------------
// Fallback out (ws too small for pe table): inline trig, R5 layout.
// ---------------------------------------------------------------------------
__global__ __launch_bounds__(256)
void out_kernel_trig(const int*   __restrict__ tok,
                     const int*   __restrict__ seg,
                     const float* __restrict__ emb,
                     float*       __restrict__ out) {
    const int bid = (int)blockIdx.x;
    const int vb  = ((bid & 7) << 11) | (bid >> 3);

    const int lane = (int)threadIdx.x & 63;
    const int row  = __builtin_amdgcn_readfirstlane(
                        vb * 4 + ((int)threadIdx.x >> 6));

    const int   token = tok[row];
    const float segf  = (float)seg[row];

    const int dA = lane << 2;
    const int dB = dA + 256;

    const float* erow = emb + (size_t)token * DIM;
    const f32x4 eA = *reinterpret_cast<const f32x4*>(erow + dA);
    const f32x4 eB = *reinterpret_cast<const f32x4*>(erow + dB);

    float vA[4], vB[4];
    #pragma unroll
    for (int j = 0; j < 2; ++j) {
        const float kA = (float)((dA >> 1) + j);
        const float divA = __builtin_amdgcn_exp2f(C2 * kA);
        float rA = segf * divA * INV2PI;  rA -= floorf(rA);
        vA[2 * j]     = __builtin_amdgcn_sinf(rA);
        vA[2 * j + 1] = __builtin_amdgcn_cosf(rA);

        const float kB = (float)((dB >> 1) + j);
        const float divB = __builtin_amdgcn_exp2f(C2 * kB);
        float rB = segf * divB * INV2PI;  rB -= floorf(rB);
        vB[2 * j]     = __builtin_amdgcn_sinf(rB);
        vB[2 * j + 1] = __builtin_amdgcn_cosf(rB);
    }

    f32x4 oA, oB;
    oA.x = eA.x * SQRT_DIM + vA[0];  oA.y = eA.y * SQRT_DIM + vA[1];
    oA.z = eA.z * SQRT_DIM + vA[2];  oA.w = eA.w * SQRT_DIM + vA[3];
    oB.x = eB.x * SQRT_DIM + vB[0];  oB.y = eB.y * SQRT_DIM + vB[1];
    oB.z = eB.z * SQRT_DIM + vB[2];  oB.w = eB.w * SQRT_DIM + vB[3];

    float* orow = out + (size_t)row * DIM;
    __builtin_nontemporal_store(oA, reinterpret_cast<f32x4*>(orow + dA));
    __builtin_nontemporal_store(oB, reinterpret_cast<f32x4*>(orow + dB));
}

extern "C" void kernel_launch(void* const* d_in, const int* in_sizes, int n_in,
                              void* d_out, int out_size, void* d_ws, size_t ws_size,
                              hipStream_t stream) {
    const int*   tok = (const int*)d_in[0];     // (BATCH, SEQ) int32
    const float* emb = (const float*)d_in[1];   // (VOCAB, DIM) f32
    float*       out = (float*)d_out;           // (BATCH, SEQ, DIM) f32
    int*            seg = (int*)d_ws;
    unsigned short* pe  = (unsigned short*)((char*)d_ws + SEG_BYTES);

    const bool have_pe_ws = (ws_size >= SEG_BYTES + PE_BYTES);

    if (have_pe_ws) {
        prep_kernel<<<BATCH + PE_BLOCKS, TPB_PREP, 0, stream>>>(tok, seg, pe);
        out_kernel<<<OUT_BLOCKS, 256, 0, stream>>>(tok, seg, emb, pe, out);
    } else {
        prep_kernel<<<BATCH, TPB_PREP, 0, stream>>>(tok, seg, pe);
        out_kernel_trig<<<OUT_BLOCKS, 256, 0, stream>>>(tok, seg, emb, out);
    }
}